// Round 1
// baseline (1091.535 us; speedup 1.0000x reference)
//
#include <hip/hip_runtime.h>
#include <hip/hip_bf16.h>

#define H 65536
#define DIMC 384

typedef __bf16 bf16x8 __attribute__((ext_vector_type(8)));
typedef float f32x4 __attribute__((ext_vector_type(4)));

__device__ __forceinline__ unsigned short f2bf(float x) {
    return __builtin_bit_cast(unsigned short, __float2bfloat16(x));
}
__device__ __forceinline__ float bf2f(unsigned short u) {
    return __bfloat162float(__builtin_bit_cast(__hip_bfloat16, u));
}

// ---------------------------------------------------------------------------
// Weight convert: f32 -> bf16, cc_w1 padded 882 -> 896 with zeros.
// blockIdx.y selects matrix. Region layout (elements):
//   w1b [384*896] | w2b,w3b,c11b,c12b,c21b,c22b [384*384] each
// ---------------------------------------------------------------------------
__global__ __launch_bounds__(256) void wconv_k(
    const float* __restrict__ w1, const float* __restrict__ w2, const float* __restrict__ w3,
    const float* __restrict__ c11, const float* __restrict__ c12,
    const float* __restrict__ c21, const float* __restrict__ c22,
    unsigned short* __restrict__ dst)
{
    int m = blockIdx.y;
    const float* src; unsigned short* d; int K, Kp;
    if (m == 0) { src = w1; d = dst; K = 882; Kp = 896; }
    else {
        switch (m) {
            case 1: src = w2;  break;
            case 2: src = w3;  break;
            case 3: src = c11; break;
            case 4: src = c12; break;
            case 5: src = c21; break;
            default: src = c22; break;
        }
        K = 384; Kp = 384;
        d = dst + 344064 + (m - 1) * 147456;
    }
    int gid = blockIdx.x * 256 + threadIdx.x;
    if (gid < 384 * Kp) {
        int n = gid / Kp;
        int k = gid - n * Kp;
        d[gid] = f2bf(k < K ? src[n * K + k] : 0.f);
    }
}

// ---------------------------------------------------------------------------
// corr [882, H] f32  ->  [H, 896] bf16 (transpose + convert, zero pad k>=882)
// ---------------------------------------------------------------------------
__global__ __launch_bounds__(256) void corr_tconv(const float* __restrict__ src,
                                                  unsigned short* __restrict__ dst)
{
    __shared__ float tile[64][65];
    int hb = blockIdx.x * 64;
    int kb = blockIdx.y * 64;
    int t = threadIdx.x;
    int col = t & 63, r4 = t >> 6;
    #pragma unroll
    for (int p = 0; p < 16; ++p) {
        int row = p * 4 + r4;          // k offset
        int k = kb + row;
        tile[row][col] = (k < 882) ? src[(size_t)k * H + hb + col] : 0.f;
    }
    __syncthreads();
    #pragma unroll
    for (int p = 0; p < 16; ++p) {
        int hrow = p * 4 + r4;         // h offset
        dst[(size_t)(hb + hrow) * 896 + kb + col] = f2bf(tile[col][hrow]);
    }
}

// ---------------------------------------------------------------------------
// ni = (net + inp) : [384, H] f32 x2  ->  [H, 384] f32 (transpose + add)
// ---------------------------------------------------------------------------
__global__ __launch_bounds__(256) void ni_t(const float* __restrict__ a,
                                            const float* __restrict__ b,
                                            float* __restrict__ dst)
{
    __shared__ float tile[64][65];
    int hb = blockIdx.x * 64;
    int cb = blockIdx.y * 64;
    int t = threadIdx.x;
    int col = t & 63, r4 = t >> 6;
    #pragma unroll
    for (int p = 0; p < 16; ++p) {
        int row = p * 4 + r4;          // c offset
        size_t g = (size_t)(cb + row) * H + hb + col;
        tile[row][col] = a[g] + b[g];
    }
    __syncthreads();
    #pragma unroll
    for (int p = 0; p < 16; ++p) {
        int hrow = p * 4 + r4;
        dst[(size_t)(hb + hrow) * DIMC + cb + col] = tile[col][hrow];
    }
}

// ---------------------------------------------------------------------------
// xout [H,384] f32 -> net_out [384, H] f32 (transpose)
// ---------------------------------------------------------------------------
__global__ __launch_bounds__(256) void xout_t(const float* __restrict__ src,
                                              float* __restrict__ dst)
{
    __shared__ float tile[64][65];
    int hb = blockIdx.x * 64;
    int cb = blockIdx.y * 64;
    int t = threadIdx.x;
    int col = t & 63, r4 = t >> 6;
    #pragma unroll
    for (int p = 0; p < 16; ++p) {
        int row = p * 4 + r4;          // h offset
        tile[row][col] = src[(size_t)(hb + row) * DIMC + cb + col];
    }
    __syncthreads();
    #pragma unroll
    for (int p = 0; p < 16; ++p) {
        int crow = p * 4 + r4;         // c offset
        dst[(size_t)(cb + crow) * H + hb + col] = tile[col][crow];
    }
}

// ---------------------------------------------------------------------------
// GEMM: out[h, c] = sum_k Act[h,k] * W[c,k] + bias[c]   (h-tile 128, c-tile 128)
// MODE 0: outb = bf16(relu(v))
// MODE 1: v += auxf[h,c];        outf = v, outb = bf16(v)      (trunk build)
// MODE 2: outb = bf16(v)                                        (v1 branch)
// MODE 3: v += auxf + bf2f(auxb); outf = v, outb = bf16(relu(v)) (final combine)
// Weights are the MFMA A operand (m = c), activations the B operand (n = h):
//   A[m=lane&15][k=quad*8+j], B[k=quad*8+j][n=lane&15],
//   D: col(n=h)=lane&15, row(m=c)=quad*4+reg  -> 4 accs are consecutive channels.
// ---------------------------------------------------------------------------
template<int MODE>
__global__ __launch_bounds__(256) void gemm_k(
    const unsigned short* __restrict__ W,    // [384, Kp] bf16
    const unsigned short* __restrict__ A,    // [H, Kp]  bf16
    const float* __restrict__ bias,          // [384]
    const float* __restrict__ auxf,          // [H,384] f32  (MODE 1,3)
    const unsigned short* __restrict__ auxb, // [H,384] bf16 (MODE 3)
    unsigned short* __restrict__ outb,       // [H,384] bf16
    float* __restrict__ outf,                // [H,384] f32  (MODE 1,3)
    int Kp)
{
    __shared__ unsigned short Wt[128 * 32];
    __shared__ unsigned short At[128 * 32];
    const int tid  = threadIdx.x;
    const int lane = tid & 63;
    const int wave = tid >> 6;
    const int quad = lane >> 4;
    const int l15  = lane & 15;
    const int h0 = blockIdx.x * 128;
    const int c0 = blockIdx.y * 128;
    const int cw = (wave & 1) * 64;
    const int hw = (wave >> 1) * 64;

    const unsigned short* Wbase = W + (size_t)c0 * Kp;
    const unsigned short* Abase = A + (size_t)h0 * Kp;

    f32x4 acc[4][4];
    #pragma unroll
    for (int i = 0; i < 4; ++i)
        #pragma unroll
        for (int j = 0; j < 4; ++j)
            acc[i][j] = f32x4{0.f, 0.f, 0.f, 0.f};

    const int row_l = tid >> 2;        // 0..63
    const int k8    = (tid & 3) * 8;   // k element offset within 32-chunk

    for (int kt = 0; kt < Kp; kt += 32) {
        __syncthreads();
        // Stage W tile (128x32) and Act tile (128x32): lane l of wave w writes
        // LDS at base + lane*16; base = (iter*256 + wave*64)*16 matches row*64+k8*2.
        {
            const unsigned short* g0 = Wbase + (size_t)row_l * Kp + kt + k8;
            const unsigned short* g1 = Wbase + (size_t)(row_l + 64) * Kp + kt + k8;
            char* lb0 = (char*)Wt + (wave * 64) * 16;
            char* lb1 = (char*)Wt + (256 + wave * 64) * 16;
            __builtin_amdgcn_global_load_lds((__attribute__((address_space(1))) void*)(void*)g0,
                                             (__attribute__((address_space(3))) void*)lb0, 16, 0, 0);
            __builtin_amdgcn_global_load_lds((__attribute__((address_space(1))) void*)(void*)g1,
                                             (__attribute__((address_space(3))) void*)lb1, 16, 0, 0);
            const unsigned short* a0 = Abase + (size_t)row_l * Kp + kt + k8;
            const unsigned short* a1 = Abase + (size_t)(row_l + 64) * Kp + kt + k8;
            char* la0 = (char*)At + (wave * 64) * 16;
            char* la1 = (char*)At + (256 + wave * 64) * 16;
            __builtin_amdgcn_global_load_lds((__attribute__((address_space(1))) void*)(void*)a0,
                                             (__attribute__((address_space(3))) void*)la0, 16, 0, 0);
            __builtin_amdgcn_global_load_lds((__attribute__((address_space(1))) void*)(void*)a1,
                                             (__attribute__((address_space(3))) void*)la1, 16, 0, 0);
        }
        __syncthreads();

        uint4 aw[4], bx[4];
        const uint4* Wv = (const uint4*)Wt;
        const uint4* Av = (const uint4*)At;
        #pragma unroll
        for (int ci = 0; ci < 4; ++ci) aw[ci] = Wv[(cw + ci * 16 + l15) * 4 + quad];
        #pragma unroll
        for (int hi = 0; hi < 4; ++hi) bx[hi] = Av[(hw + hi * 16 + l15) * 4 + quad];
        #pragma unroll
        for (int ci = 0; ci < 4; ++ci)
            #pragma unroll
            for (int hi = 0; hi < 4; ++hi)
                acc[ci][hi] = __builtin_amdgcn_mfma_f32_16x16x32_bf16(
                    __builtin_bit_cast(bf16x8, aw[ci]),
                    __builtin_bit_cast(bf16x8, bx[hi]),
                    acc[ci][hi], 0, 0, 0);
    }

    // Epilogue
    #pragma unroll
    for (int ci = 0; ci < 4; ++ci) {
        const int c = c0 + cw + ci * 16 + quad * 4;
        f32x4 b4 = *(const f32x4*)(bias + c);
        #pragma unroll
        for (int hi = 0; hi < 4; ++hi) {
            const int h = h0 + hw + hi * 16 + l15;
            const size_t base = (size_t)h * DIMC + c;
            f32x4 v = acc[ci][hi] + b4;
            if constexpr (MODE == 1) {
                v += *(const f32x4*)(auxf + base);
            }
            if constexpr (MODE == 3) {
                v += *(const f32x4*)(auxf + base);
                ushort4 u = *(const ushort4*)(auxb + base);
                v[0] += bf2f(u.x); v[1] += bf2f(u.y);
                v[2] += bf2f(u.z); v[3] += bf2f(u.w);
            }
            if constexpr (MODE == 1 || MODE == 3) {
                *(f32x4*)(outf + base) = v;
            }
            f32x4 s = v;
            if constexpr (MODE == 0 || MODE == 3) {
                s[0] = fmaxf(s[0], 0.f); s[1] = fmaxf(s[1], 0.f);
                s[2] = fmaxf(s[2], 0.f); s[3] = fmaxf(s[3], 0.f);
            }
            ushort4 o;
            o.x = f2bf(s[0]); o.y = f2bf(s[1]); o.z = f2bf(s[2]); o.w = f2bf(s[3]);
            *(ushort4*)(outb + base) = o;
        }
    }
}

// ---------------------------------------------------------------------------
// Heads: wave per h. d = r@dW^T + dB ; w = sigmoid(r@wW^T + wB)
// r is [H,384] bf16. Output layout: out[384H + {0,1}H + h], out[386H + {0,1}H + h]
// ---------------------------------------------------------------------------
__global__ __launch_bounds__(256) void heads_k(
    const unsigned short* __restrict__ r,
    const float* __restrict__ dW, const float* __restrict__ dB,
    const float* __restrict__ wW, const float* __restrict__ wB,
    float* __restrict__ out)
{
    __shared__ float wl[1536];
    int tid = threadIdx.x;
    for (int i = tid; i < 1536; i += 256)
        wl[i] = (i < 768) ? dW[i] : wW[i - 768];
    __syncthreads();
    int wave = tid >> 6, lane = tid & 63;
    int h = blockIdx.x * 4 + wave;
    const unsigned short* rp = r + (size_t)h * 384 + lane * 6;
    int c = lane * 6;
    float s0 = 0.f, s1 = 0.f, s2 = 0.f, s3 = 0.f;
    #pragma unroll
    for (int i = 0; i < 6; ++i) {
        float rv = bf2f(rp[i]);
        s0 += rv * wl[c + i];
        s1 += rv * wl[384 + c + i];
        s2 += rv * wl[768 + c + i];
        s3 += rv * wl[1152 + c + i];
    }
    #pragma unroll
    for (int m = 32; m >= 1; m >>= 1) {
        s0 += __shfl_xor(s0, m, 64);
        s1 += __shfl_xor(s1, m, 64);
        s2 += __shfl_xor(s2, m, 64);
        s3 += __shfl_xor(s3, m, 64);
    }
    if (lane == 0) {
        float* od = out + (size_t)384 * H;
        float* ow = out + (size_t)386 * H;
        od[h]     = s0 + dB[0];
        od[H + h] = s1 + dB[1];
        ow[h]     = 1.f / (1.f + __expf(-(s2 + wB[0])));
        ow[H + h] = 1.f / (1.f + __expf(-(s3 + wB[1])));
    }
}

// ---------------------------------------------------------------------------
extern "C" void kernel_launch(void* const* d_in, const int* in_sizes, int n_in,
                              void* d_out, int out_size, void* d_ws, size_t ws_size,
                              hipStream_t stream)
{
    const float* net   = (const float*)d_in[0];
    const float* inp   = (const float*)d_in[1];
    const float* corr  = (const float*)d_in[2];
    // d_in[3..6] = ii, jj, kk, kw: dummy path multiplied by 0.0 -> unused
    const float* cc_w1 = (const float*)d_in[7];
    const float* cc_b1 = (const float*)d_in[8];
    const float* cc_w2 = (const float*)d_in[9];
    const float* cc_b2 = (const float*)d_in[10];
    const float* cc_w3 = (const float*)d_in[11];
    const float* cc_b3 = (const float*)d_in[12];
    const float* c1_w1 = (const float*)d_in[13];
    const float* c1_b1 = (const float*)d_in[14];
    const float* c1_w2 = (const float*)d_in[15];
    const float* c1_b2 = (const float*)d_in[16];
    const float* c2_w1 = (const float*)d_in[17];
    const float* c2_b1 = (const float*)d_in[18];
    const float* c2_w2 = (const float*)d_in[19];
    const float* c2_b2 = (const float*)d_in[20];
    const float* d_wp  = (const float*)d_in[21];
    const float* d_bp  = (const float*)d_in[22];
    const float* w_wp  = (const float*)d_in[23];
    const float* w_bp  = (const float*)d_in[24];
    float* out = (float*)d_out;

    char* ws = (char*)d_ws;
    size_t off = 0;
    auto carve = [&](size_t bytes) -> char* {
        char* p = ws + off;
        off += (bytes + 255) & ~(size_t)255;
        return p;
    };
    unsigned short* Wreg  = (unsigned short*)carve((size_t)1228800 * 2);   // bf16 weights
    unsigned short* corrb = (unsigned short*)carve((size_t)H * 896 * 2);   // corr^T bf16 (alias: u2)
    float*          nib   = (float*)carve((size_t)H * 384 * 4);            // net+inp   (alias: xout)
    unsigned short* t1    = (unsigned short*)carve((size_t)H * 384 * 2);   // t1 / u1 / r
    unsigned short* t2    = (unsigned short*)carve((size_t)H * 384 * 2);   // t2 / v1
    float*          xf    = (float*)carve((size_t)H * 384 * 4);            // f32 trunk x
    unsigned short* xb    = (unsigned short*)carve((size_t)H * 384 * 2);   // bf16 trunk x

    unsigned short* w1b  = Wreg;
    unsigned short* w2b  = Wreg + 344064;
    unsigned short* w3b  = w2b + 147456;
    unsigned short* c11b = w3b + 147456;
    unsigned short* c12b = c11b + 147456;
    unsigned short* c21b = c12b + 147456;
    unsigned short* c22b = c21b + 147456;

    wconv_k<<<dim3(1344, 7), 256, 0, stream>>>(cc_w1, cc_w2, cc_w3, c1_w1, c1_w2, c2_w1, c2_w2, Wreg);
    corr_tconv<<<dim3(1024, 14), 256, 0, stream>>>(corr, corrb);
    ni_t<<<dim3(1024, 6), 256, 0, stream>>>(net, inp, nib);

    // cc chain
    gemm_k<0><<<dim3(512, 3), 256, 0, stream>>>(w1b, corrb, cc_b1, nullptr, nullptr, t1, nullptr, 896);
    gemm_k<0><<<dim3(512, 3), 256, 0, stream>>>(w2b, t1, cc_b2, nullptr, nullptr, t2, nullptr, 384);
    // trunk: x = net + inp + cc  (f32 xf + bf16 xb)
    gemm_k<1><<<dim3(512, 3), 256, 0, stream>>>(w3b, t2, cc_b3, nib, nullptr, xb, xf, 384);
    // branch 1
    gemm_k<0><<<dim3(512, 3), 256, 0, stream>>>(c11b, xb, c1_b1, nullptr, nullptr, t1, nullptr, 384);
    gemm_k<2><<<dim3(512, 3), 256, 0, stream>>>(c12b, t1, c1_b2, nullptr, nullptr, t2, nullptr, 384);
    // branch 2 (u2 into dead corr buffer)
    gemm_k<0><<<dim3(512, 3), 256, 0, stream>>>(c21b, xb, c2_b1, nullptr, nullptr, corrb, nullptr, 384);
    // final combine: xout = x + v1 + v2 (f32 -> nib), r = relu(xout) bf16 -> t1
    gemm_k<3><<<dim3(512, 3), 256, 0, stream>>>(c22b, corrb, c2_b2, xf, t2, t1, nib, 384);

    xout_t<<<dim3(1024, 6), 256, 0, stream>>>(nib, out);
    heads_k<<<H / 4, 256, 0, stream>>>(t1, d_wp, d_bp, w_wp, w_bp, out);
}

// Round 2
// 1013.768 us; speedup vs baseline: 1.0767x; 1.0767x over previous
//
#include <hip/hip_runtime.h>
#include <hip/hip_bf16.h>

#define H 65536
#define DIMC 384

typedef __bf16 bf16x8 __attribute__((ext_vector_type(8)));
typedef float f32x4 __attribute__((ext_vector_type(4)));

__device__ __forceinline__ unsigned short f2bf(float x) {
    return __builtin_bit_cast(unsigned short, __float2bfloat16(x));
}
__device__ __forceinline__ float bf2f(unsigned short u) {
    return __bfloat162float(__builtin_bit_cast(__hip_bfloat16, u));
}

// ---------------------------------------------------------------------------
// Weight convert: f32 -> bf16, cc_w1 padded 882 -> 896 with zeros.
// ---------------------------------------------------------------------------
__global__ __launch_bounds__(256) void wconv_k(
    const float* __restrict__ w1, const float* __restrict__ w2, const float* __restrict__ w3,
    const float* __restrict__ c11, const float* __restrict__ c12,
    const float* __restrict__ c21, const float* __restrict__ c22,
    unsigned short* __restrict__ dst)
{
    int m = blockIdx.y;
    const float* src; unsigned short* d; int K, Kp;
    if (m == 0) { src = w1; d = dst; K = 882; Kp = 896; }
    else {
        switch (m) {
            case 1: src = w2;  break;
            case 2: src = w3;  break;
            case 3: src = c11; break;
            case 4: src = c12; break;
            case 5: src = c21; break;
            default: src = c22; break;
        }
        K = 384; Kp = 384;
        d = dst + 344064 + (m - 1) * 147456;
    }
    int gid = blockIdx.x * 256 + threadIdx.x;
    if (gid < 384 * Kp) {
        int n = gid / Kp;
        int k = gid - n * Kp;
        d[gid] = f2bf(k < K ? src[n * K + k] : 0.f);
    }
}

// ---------------------------------------------------------------------------
// corr [882, H] f32  ->  [H, 896] bf16 (transpose + convert, zero pad k>=882)
// ---------------------------------------------------------------------------
__global__ __launch_bounds__(256) void corr_tconv(const float* __restrict__ src,
                                                  unsigned short* __restrict__ dst)
{
    __shared__ float tile[64][65];
    int hb = blockIdx.x * 64;
    int kb = blockIdx.y * 64;
    int t = threadIdx.x;
    int col = t & 63, r4 = t >> 6;
    #pragma unroll
    for (int p = 0; p < 16; ++p) {
        int row = p * 4 + r4;          // k offset
        int k = kb + row;
        tile[row][col] = (k < 882) ? src[(size_t)k * H + hb + col] : 0.f;
    }
    __syncthreads();
    #pragma unroll
    for (int p = 0; p < 16; ++p) {
        int hrow = p * 4 + r4;         // h offset
        dst[(size_t)(hb + hrow) * 896 + kb + col] = f2bf(tile[col][hrow]);
    }
}

// ---------------------------------------------------------------------------
// GEMM: out[h, c] = sum_k Act[h,k] * W[c,k] + bias[c]
// Tiles: 128 h x 128 c x BK=64. 256 threads = 4 waves, each wave 64h x 64c.
// MODE 0: outb = bf16(relu(v))
// MODE 1: v += net_T + inp_T (strided [c][h] f32 reads); outf = v; outb = bf16(v)
// MODE 2: outb = bf16(v)
// MODE 3: v += aux0[h,c](f32) + bf2f(auxb[h,c]); outf[(c)*H+h] = v (transposed
//         net_out store); outb = bf16(relu(v))
// Weights = MFMA A operand (m=c), activations = B operand (n=h).
//   D: col(n=h)=lane&15, row(m=c)=quad*4+reg -> 4 accs are consecutive channels.
// ---------------------------------------------------------------------------
template<int MODE>
__global__ __launch_bounds__(256) void gemm_k(
    const unsigned short* __restrict__ W,    // [384, Kp] bf16
    const unsigned short* __restrict__ A,    // [H, Kp]  bf16
    const float* __restrict__ bias,          // [384]
    const float* __restrict__ aux0,          // MODE1: net [384,H]; MODE3: xf [H,384]
    const float* __restrict__ aux1,          // MODE1: inp [384,H]
    const unsigned short* __restrict__ auxb, // MODE3: b1 bf16 [H,384]
    unsigned short* __restrict__ outb,       // [H,384] bf16
    float* __restrict__ outf,                // MODE1: xf [H,384]; MODE3: net_out [384,H]
    int Kp)
{
    __shared__ unsigned short Wt[128 * 64];
    __shared__ unsigned short At[128 * 64];
    const int tid  = threadIdx.x;
    const int lane = tid & 63;
    const int wave = tid >> 6;
    const int quad = lane >> 4;
    const int l15  = lane & 15;
    const int h0 = blockIdx.x * 128;
    const int c0 = blockIdx.y * 128;
    const int cw = (wave & 1) * 64;
    const int hw = (wave >> 1) * 64;

    const unsigned short* Wbase = W + (size_t)c0 * Kp;
    const unsigned short* Abase = A + (size_t)h0 * Kp;

    f32x4 acc[4][4];
    #pragma unroll
    for (int i = 0; i < 4; ++i)
        #pragma unroll
        for (int j = 0; j < 4; ++j)
            acc[i][j] = f32x4{0.f, 0.f, 0.f, 0.f};

    // Staging decomposition: tile row stride 64 bf16 = 128 B = 8 x 16B slots.
    // slot s = i*256 + tid  ->  row = i*32 + (tid>>3), k-elem = (tid&7)*8.
    const int srow = tid >> 3;
    const int skc  = (tid & 7) * 8;

    for (int kt = 0; kt < Kp; kt += 64) {
        __syncthreads();
        #pragma unroll
        for (int i = 0; i < 4; ++i) {
            const unsigned short* g = Wbase + (size_t)(i * 32 + srow) * Kp + kt + skc;
            char* lb = (char*)Wt + (i * 256 + wave * 64) * 16;
            __builtin_amdgcn_global_load_lds((__attribute__((address_space(1))) void*)(void*)g,
                                             (__attribute__((address_space(3))) void*)lb, 16, 0, 0);
        }
        #pragma unroll
        for (int i = 0; i < 4; ++i) {
            const unsigned short* g = Abase + (size_t)(i * 32 + srow) * Kp + kt + skc;
            char* lb = (char*)At + (i * 256 + wave * 64) * 16;
            __builtin_amdgcn_global_load_lds((__attribute__((address_space(1))) void*)(void*)g,
                                             (__attribute__((address_space(3))) void*)lb, 16, 0, 0);
        }
        __syncthreads();

        const uint4* Wv = (const uint4*)Wt;
        const uint4* Av = (const uint4*)At;
        #pragma unroll
        for (int ks = 0; ks < 2; ++ks) {
            uint4 aw[4], bx[4];
            #pragma unroll
            for (int ci = 0; ci < 4; ++ci) aw[ci] = Wv[(cw + ci * 16 + l15) * 8 + ks * 4 + quad];
            #pragma unroll
            for (int hi = 0; hi < 4; ++hi) bx[hi] = Av[(hw + hi * 16 + l15) * 8 + ks * 4 + quad];
            #pragma unroll
            for (int ci = 0; ci < 4; ++ci)
                #pragma unroll
                for (int hi = 0; hi < 4; ++hi)
                    acc[ci][hi] = __builtin_amdgcn_mfma_f32_16x16x32_bf16(
                        __builtin_bit_cast(bf16x8, aw[ci]),
                        __builtin_bit_cast(bf16x8, bx[hi]),
                        acc[ci][hi], 0, 0, 0);
        }
    }

    // Epilogue
    #pragma unroll
    for (int ci = 0; ci < 4; ++ci) {
        const int c = c0 + cw + ci * 16 + quad * 4;
        f32x4 b4 = *(const f32x4*)(bias + c);
        #pragma unroll
        for (int hi = 0; hi < 4; ++hi) {
            const int h = h0 + hw + hi * 16 + l15;
            const size_t base = (size_t)h * DIMC + c;
            f32x4 v = acc[ci][hi] + b4;
            if constexpr (MODE == 1) {
                // fused transpose-read of net & inp ([384,H] layout)
                #pragma unroll
                for (int r = 0; r < 4; ++r)
                    v[r] += aux0[(size_t)(c + r) * H + h] + aux1[(size_t)(c + r) * H + h];
            }
            if constexpr (MODE == 3) {
                v += *(const f32x4*)(aux0 + base);
                ushort4 u = *(const ushort4*)(auxb + base);
                v[0] += bf2f(u.x); v[1] += bf2f(u.y);
                v[2] += bf2f(u.z); v[3] += bf2f(u.w);
            }
            if constexpr (MODE == 1) {
                *(f32x4*)(outf + base) = v;
            }
            if constexpr (MODE == 3) {
                // fused transposed store: net_out[c][h]
                #pragma unroll
                for (int r = 0; r < 4; ++r)
                    outf[(size_t)(c + r) * H + h] = v[r];
            }
            f32x4 s = v;
            if constexpr (MODE == 0 || MODE == 3) {
                s[0] = fmaxf(s[0], 0.f); s[1] = fmaxf(s[1], 0.f);
                s[2] = fmaxf(s[2], 0.f); s[3] = fmaxf(s[3], 0.f);
            }
            ushort4 o;
            o.x = f2bf(s[0]); o.y = f2bf(s[1]); o.z = f2bf(s[2]); o.w = f2bf(s[3]);
            *(ushort4*)(outb + base) = o;
        }
    }
}

// ---------------------------------------------------------------------------
// Heads: wave per h. d = r@dW^T + dB ; w = sigmoid(r@wW^T + wB)
// ---------------------------------------------------------------------------
__global__ __launch_bounds__(256) void heads_k(
    const unsigned short* __restrict__ r,
    const float* __restrict__ dW, const float* __restrict__ dB,
    const float* __restrict__ wW, const float* __restrict__ wB,
    float* __restrict__ out)
{
    __shared__ float wl[1536];
    int tid = threadIdx.x;
    for (int i = tid; i < 1536; i += 256)
        wl[i] = (i < 768) ? dW[i] : wW[i - 768];
    __syncthreads();
    int wave = tid >> 6, lane = tid & 63;
    int h = blockIdx.x * 4 + wave;
    const unsigned short* rp = r + (size_t)h * 384 + lane * 6;
    int c = lane * 6;
    float s0 = 0.f, s1 = 0.f, s2 = 0.f, s3 = 0.f;
    #pragma unroll
    for (int i = 0; i < 6; ++i) {
        float rv = bf2f(rp[i]);
        s0 += rv * wl[c + i];
        s1 += rv * wl[384 + c + i];
        s2 += rv * wl[768 + c + i];
        s3 += rv * wl[1152 + c + i];
    }
    #pragma unroll
    for (int m = 32; m >= 1; m >>= 1) {
        s0 += __shfl_xor(s0, m, 64);
        s1 += __shfl_xor(s1, m, 64);
        s2 += __shfl_xor(s2, m, 64);
        s3 += __shfl_xor(s3, m, 64);
    }
    if (lane == 0) {
        float* od = out + (size_t)384 * H;
        float* ow = out + (size_t)386 * H;
        od[h]     = s0 + dB[0];
        od[H + h] = s1 + dB[1];
        ow[h]     = 1.f / (1.f + __expf(-(s2 + wB[0])));
        ow[H + h] = 1.f / (1.f + __expf(-(s3 + wB[1])));
    }
}

// ---------------------------------------------------------------------------
extern "C" void kernel_launch(void* const* d_in, const int* in_sizes, int n_in,
                              void* d_out, int out_size, void* d_ws, size_t ws_size,
                              hipStream_t stream)
{
    const float* net   = (const float*)d_in[0];
    const float* inp   = (const float*)d_in[1];
    const float* corr  = (const float*)d_in[2];
    // d_in[3..6] = ii, jj, kk, kw: dummy path multiplied by 0.0 -> unused
    const float* cc_w1 = (const float*)d_in[7];
    const float* cc_b1 = (const float*)d_in[8];
    const float* cc_w2 = (const float*)d_in[9];
    const float* cc_b2 = (const float*)d_in[10];
    const float* cc_w3 = (const float*)d_in[11];
    const float* cc_b3 = (const float*)d_in[12];
    const float* c1_w1 = (const float*)d_in[13];
    const float* c1_b1 = (const float*)d_in[14];
    const float* c1_w2 = (const float*)d_in[15];
    const float* c1_b2 = (const float*)d_in[16];
    const float* c2_w1 = (const float*)d_in[17];
    const float* c2_b1 = (const float*)d_in[18];
    const float* c2_w2 = (const float*)d_in[19];
    const float* c2_b2 = (const float*)d_in[20];
    const float* d_wp  = (const float*)d_in[21];
    const float* d_bp  = (const float*)d_in[22];
    const float* w_wp  = (const float*)d_in[23];
    const float* w_bp  = (const float*)d_in[24];
    float* out = (float*)d_out;

    char* ws = (char*)d_ws;
    size_t off = 0;
    auto carve = [&](size_t bytes) -> char* {
        char* p = ws + off;
        off += (bytes + 255) & ~(size_t)255;
        return p;
    };
    unsigned short* Wreg  = (unsigned short*)carve((size_t)1228800 * 2);   // bf16 weights
    unsigned short* corrb = (unsigned short*)carve((size_t)H * 896 * 2);   // corr^T bf16 (alias: u2)
    unsigned short* t1    = (unsigned short*)carve((size_t)H * 384 * 2);   // t1 / u1 / r
    unsigned short* t2    = (unsigned short*)carve((size_t)H * 384 * 2);   // t2 / v1
    float*          xf    = (float*)carve((size_t)H * 384 * 4);            // f32 trunk x
    unsigned short* xb    = (unsigned short*)carve((size_t)H * 384 * 2);   // bf16 trunk x

    unsigned short* w1b  = Wreg;
    unsigned short* w2b  = Wreg + 344064;
    unsigned short* w3b  = w2b + 147456;
    unsigned short* c11b = w3b + 147456;
    unsigned short* c12b = c11b + 147456;
    unsigned short* c21b = c12b + 147456;
    unsigned short* c22b = c21b + 147456;

    wconv_k<<<dim3(1344, 7), 256, 0, stream>>>(cc_w1, cc_w2, cc_w3, c1_w1, c1_w2, c2_w1, c2_w2, Wreg);
    corr_tconv<<<dim3(1024, 14), 256, 0, stream>>>(corr, corrb);

    // cc chain
    gemm_k<0><<<dim3(512, 3), 256, 0, stream>>>(w1b, corrb, cc_b1, nullptr, nullptr, nullptr, t1, nullptr, 896);
    gemm_k<0><<<dim3(512, 3), 256, 0, stream>>>(w2b, t1, cc_b2, nullptr, nullptr, nullptr, t2, nullptr, 384);
    // trunk: x = net + inp + cc  (fused transpose-read of net/inp; f32 xf + bf16 xb)
    gemm_k<1><<<dim3(512, 3), 256, 0, stream>>>(w3b, t2, cc_b3, net, inp, nullptr, xb, xf, 384);
    // branch 1
    gemm_k<0><<<dim3(512, 3), 256, 0, stream>>>(c11b, xb, c1_b1, nullptr, nullptr, nullptr, t1, nullptr, 384);
    gemm_k<2><<<dim3(512, 3), 256, 0, stream>>>(c12b, t1, c1_b2, nullptr, nullptr, nullptr, t2, nullptr, 384);
    // branch 2 (u2 into dead corr buffer)
    gemm_k<0><<<dim3(512, 3), 256, 0, stream>>>(c21b, xb, c2_b1, nullptr, nullptr, nullptr, corrb, nullptr, 384);
    // final combine: x_out = x + v1 + v2 -> transposed store to out; r = relu bf16 -> t1
    gemm_k<3><<<dim3(512, 3), 256, 0, stream>>>(c22b, corrb, c2_b2, xf, nullptr, t2, t1, out, 384);

    heads_k<<<H / 4, 256, 0, stream>>>(t1, d_wp, d_bp, w_wp, w_bp, out);
}